// Round 10
// baseline (756.481 us; speedup 1.0000x reference)
//
#include <hip/hip_runtime.h>
#include <hip/hip_bf16.h>

typedef __hip_bfloat16 bf16;
typedef __attribute__((ext_vector_type(8))) short bf16x8_t;
typedef __attribute__((ext_vector_type(4))) float f32x4_t;

__device__ __forceinline__ float b2f(bf16 v){ return __bfloat162float(v); }
__device__ __forceinline__ bf16 f2b(float v){ return __float2bfloat16(v); }
__device__ __forceinline__ short tobits(float v){ bf16 b = f2b(v); return *(short*)&b; }
__device__ __forceinline__ float us2f(ushort u){ return __uint_as_float(((unsigned)u)<<16); }
__device__ __forceinline__ ushort f2us(float v){ bf16 b = f2b(v); return *(ushort*)&b; }

#define NN 50000
#define NE 250000
#define NEA 500000
#define NR 300
#define EHD 300
#define THD 100
#define RHD 100
#define RCH 8
#define NBN 98      // node buckets (512 wide)
#define NBR 75      // rel buckets (4 wide)
#define HB 245      // histogram blocks per segment

__device__ __forceinline__ int clampi(int v, int n){ return ((unsigned)v < (unsigned)n) ? v : 0; }

__device__ __forceinline__ float wred_sum(float p){
    #pragma unroll
    for(int m=32;m>=1;m>>=1) p += __shfl_xor(p, m);
    return p;
}
__device__ __forceinline__ float wred_max(float p){
    #pragma unroll
    for(int m=32;m>=1;m>>=1) p = fmaxf(p, __shfl_xor(p, m));
    return p;
}

// ---------- fused prep: bf16 cast of x | 3 weight transposes | bucket histograms ----------
__global__ void k_prep(const float4* __restrict__ xin4, ushort* __restrict__ xFu,
                       const float* __restrict__ hw1w, const float* __restrict__ hw2w,
                       const float* __restrict__ tc1w,
                       short* __restrict__ Wt1, short* __restrict__ Wt2, short* __restrict__ Wtc,
                       const int* __restrict__ ji, const int* __restrict__ ht,
                       const int* __restrict__ rel, int* __restrict__ bhist){
    int bx = blockIdx.x, tid = threadIdx.x;
    int i = bx*256 + tid;
    const int N4 = NN*EHD/4;
    if(i < N4){
        float4 v = xin4[i];
        ushort4 o;
        o.x = (ushort)tobits(v.x); o.y = (ushort)tobits(v.y);
        o.z = (ushort)tobits(v.z); o.w = (ushort)tobits(v.w);
        *(ushort4*)(xFu + 4*(size_t)i) = o;
    }
    const int S1 = EHD*EHD, S2 = 2*EHD*EHD, S3 = 2*EHD*EHD + EHD*THD;
    if(i < S1){
        int n = i/EHD, k = i - n*EHD;
        Wt1[i] = tobits(hw1w[(size_t)k*EHD + n]);
    } else if(i < S2){
        int ii = i - S1; int n = ii/EHD, k = ii - n*EHD;
        Wt2[ii] = tobits(hw2w[(size_t)k*EHD + n]);
    } else if(i < S3){
        int ii = i - S2; int n = ii/EHD, k = ii - n*EHD;
        Wtc[ii] = tobits(tc1w[(size_t)k*THD + n]);
    }
    // bucket histograms: blocks [0, 4*HB)
    if(bx < 4*HB){
        int s = bx / HB, cb = bx - s*HB;
        __shared__ int h[128];
        if(tid < 128) h[tid] = 0;
        __syncthreads();
        int n_s = (s == 0) ? NEA : NE;
        int base_e = cb*2048;
        int shift = (s < 3) ? 9 : 2;
        if(base_e < n_s){
            #pragma unroll
            for(int u=0;u<8;u++){
                int e = base_e + u*256 + tid;
                if(e < n_s){
                    int key;
                    if(s == 0) key = clampi(ji[NEA + e], NN);
                    else if(s == 1) key = clampi(ht[e], NN);
                    else if(s == 2) key = clampi(ht[NE + e], NN);
                    else key = clampi(rel[e], NR);
                    atomicAdd(&h[key >> shift], 1);
                }
            }
        }
        __syncthreads();
        if(tid < 128) bhist[((size_t)s*HB + cb)*128 + tid] = h[tid];
    }
}

// ---------- reduce histograms + segmented scan -> gbase[4][129], gcur[4][128] ----------
__global__ void k_bscan(const int* __restrict__ bhist, int* __restrict__ gbase, int* __restrict__ gcur){
    __shared__ int lds[512];
    int tid = threadIdx.x;   // 512
    int s = tid >> 7, b = tid & 127;
    int v = 0;
    for(int cb=0; cb<HB; cb++) v += bhist[((size_t)s*HB + cb)*128 + b];
    lds[tid] = v; __syncthreads();
    for(int st=1; st<128; st<<=1){
        int add = ((tid & 127) >= st) ? lds[tid-st] : 0;
        __syncthreads();
        lds[tid] += add;
        __syncthreads();
    }
    int excl = lds[tid] - v;
    gbase[s*129 + b] = excl;
    gcur[s*128 + b] = excl;
    if(b == 127) gbase[s*129 + 128] = lds[tid];
}

// ---------- Phase C: LDS-staged binning into bucket-ordered tmp (int2 = key,payload) ----------
__global__ __launch_bounds__(256) void k_bin(const int* __restrict__ ji, const int* __restrict__ ht,
                      const int* __restrict__ rel, int* __restrict__ gcur,
                      int2* __restrict__ t0, int2* __restrict__ t1,
                      int2* __restrict__ t2, int2* __restrict__ t3){
    int s = blockIdx.y;
    int n_s = (s == 0) ? NEA : NE;
    int base_e = blockIdx.x*2048;
    if(base_e >= n_s) return;
    int shift = (s < 3) ? 9 : 2;
    int tid = threadIdx.x;
    __shared__ int cnt[128], lof[128], base[128];
    __shared__ int2 buf[2048];
    if(tid < 128) cnt[tid] = 0;
    __syncthreads();
    int kk[8], pp[8], bb[8], ss[8];
    #pragma unroll
    for(int u=0;u<8;u++){
        int e = base_e + u*256 + tid;
        bb[u] = -1;
        if(e < n_s){
            int key, pay;
            if(s == 0){ key = clampi(ji[NEA + e], NN); pay = clampi(ji[e], NN); }
            else if(s == 1){ key = clampi(ht[e], NN); pay = clampi(rel[e], NR); }
            else if(s == 2){ key = clampi(ht[NE + e], NN); pay = clampi(rel[e], NR); }
            else { key = clampi(rel[e], NR); pay = e; }
            int b = key >> shift;
            kk[u] = key; pp[u] = pay; bb[u] = b;
            ss[u] = atomicAdd(&cnt[b], 1);
        }
    }
    __syncthreads();
    if(tid == 0){
        int run = 0;
        for(int b=0;b<128;b++){ lof[b] = run; run += cnt[b]; }
    }
    __syncthreads();
    #pragma unroll
    for(int u=0;u<8;u++){
        if(bb[u] >= 0){
            int pos = lof[bb[u]] + ss[u];
            buf[pos] = make_int2(kk[u], pp[u]);
        }
    }
    __syncthreads();
    if(tid < 128 && cnt[tid] > 0) base[tid] = atomicAdd(&gcur[s*128 + tid], cnt[tid]);
    __syncthreads();
    int2* tmp = (s==0) ? t0 : (s==1) ? t1 : (s==2) ? t2 : t3;
    int total = lof[127] + cnt[127];
    for(int idx=tid; idx<total; idx+=256){
        int2 kp = buf[idx];
        int b = kp.x >> shift;
        tmp[base[b] + (idx - lof[b])] = kp;
    }
}

// ---------- Phase D: windowed CSR fill; derives off[] + dinv from binned data ----------
__global__ __launch_bounds__(256) void k_place(const int* __restrict__ gbase,
                        const int2* __restrict__ t0, const int2* __restrict__ t1,
                        const int2* __restrict__ t2, const int2* __restrict__ t3,
                        int* __restrict__ off_all, int* __restrict__ off_h,
                        int* __restrict__ off_t, int* __restrict__ off_r,
                        int* __restrict__ adj_all, int* __restrict__ adj_h,
                        int* __restrict__ adj_t, int* __restrict__ adj_r,
                        float* __restrict__ dinv){
    int s = blockIdx.y, b = blockIdx.x;
    int NB = (s < 3) ? NBN : NBR;
    if(b >= NB) return;
    int W = (s < 3) ? 512 : 4;
    int len = (s < 3) ? NN : NR;
    const int2* tmp = (s==0) ? t0 : (s==1) ? t1 : (s==2) ? t2 : t3;
    int* off = (s==0) ? off_all : (s==1) ? off_h : (s==2) ? off_t : off_r;
    int* adj = (s==0) ? adj_all : (s==1) ? adj_h : (s==2) ? adj_t : adj_r;
    int node0 = b*W;
    int node1 = node0 + W; if(node1 > len) node1 = len;
    int nloc = node1 - node0;
    int wstart = gbase[s*129 + b], wend = gbase[s*129 + b + 1];
    __shared__ int hist[512];
    __shared__ int cur[512];
    __shared__ int sb[256];
    int tid = threadIdx.x;
    for(int k=tid; k<nloc; k+=256) hist[k] = 0;
    __syncthreads();
    for(int idx = wstart + tid; idx < wend; idx += 256){
        int local = tmp[idx].x - node0;
        if((unsigned)local < (unsigned)nloc) atomicAdd(&hist[local], 1);
    }
    __syncthreads();
    int v0 = (2*tid   < nloc) ? hist[2*tid]   : 0;
    int v1 = (2*tid+1 < nloc) ? hist[2*tid+1] : 0;
    int ps = v0 + v1;
    sb[tid] = ps; __syncthreads();
    for(int st=1; st<256; st<<=1){
        int add = (tid >= st) ? sb[tid-st] : 0;
        __syncthreads();
        sb[tid] += add;
        __syncthreads();
    }
    int excl = sb[tid] - ps;
    if(2*tid < nloc){
        int o = wstart + excl;
        off[node0 + 2*tid] = o;
        cur[2*tid] = o;
        if(s == 0) dinv[node0 + 2*tid] = v0 > 0 ? rsqrtf((float)v0) : 0.f;
    }
    if(2*tid+1 < nloc){
        int o = wstart + excl + v0;
        off[node0 + 2*tid+1] = o;
        cur[2*tid+1] = o;
        if(s == 0) dinv[node0 + 2*tid+1] = v1 > 0 ? rsqrtf((float)v1) : 0.f;
    }
    if(b == NB-1 && tid == 0) off[len] = gbase[s*129 + 128];
    __syncthreads();
    for(int idx = wstart + tid; idx < wend; idx += 256){
        int2 kp = tmp[idx];
        int local = kp.x - node0;
        if((unsigned)local < (unsigned)nloc){
            int slot = atomicAdd(&cur[local], 1);
            adj[slot] = kp.y;
        }
    }
}

// ---------- GCN gather: wave per node, unroll-4, main ushort4 + tail ushort2 ----------
// lane owns dims [4L,4L+4) (L<64); lanes 0..21 also own dims 256+2L, 256+2L+1
__global__ void k_gcn(const bf16* __restrict__ xs, bf16* __restrict__ xd,
                      const int* __restrict__ off, const int* __restrict__ adjj,
                      const float* __restrict__ dinv){
    int wid = threadIdx.x >> 6, lane = threadIdx.x & 63;
    int n = blockIdx.x*4 + wid;
    if(n >= NN) return;
    float di = dinv[n];
    int s0 = off[n], s1 = off[n+1], cnt = s1 - s0;
    bool tail = lane < 22;
    float a0=0,a1=0,a2=0,a3=0, t0=0,t1=0;
    if(cnt > 0 && cnt <= 64){
        int jl = (lane < cnt) ? clampi(adjj[s0+lane], NN) : 0;
        float dl = (lane < cnt) ? dinv[jl] : 0.f;
        int it = 0;
        for(; it+4 <= cnt; it += 4){
            int j0=__shfl(jl,it), j1=__shfl(jl,it+1), j2=__shfl(jl,it+2), j3=__shfl(jl,it+3);
            float n0=di*__shfl(dl,it), n1=di*__shfl(dl,it+1), n2=di*__shfl(dl,it+2), n3=di*__shfl(dl,it+3);
            const bf16* p0 = xs + (size_t)j0*EHD;
            const bf16* p1 = xs + (size_t)j1*EHD;
            const bf16* p2 = xs + (size_t)j2*EHD;
            const bf16* p3 = xs + (size_t)j3*EHD;
            ushort4 v0=((const ushort4*)p0)[lane], v1=((const ushort4*)p1)[lane];
            ushort4 v2=((const ushort4*)p2)[lane], v3=((const ushort4*)p3)[lane];
            a0 += n0*us2f(v0.x)+n1*us2f(v1.x)+n2*us2f(v2.x)+n3*us2f(v3.x);
            a1 += n0*us2f(v0.y)+n1*us2f(v1.y)+n2*us2f(v2.y)+n3*us2f(v3.y);
            a2 += n0*us2f(v0.z)+n1*us2f(v1.z)+n2*us2f(v2.z)+n3*us2f(v3.z);
            a3 += n0*us2f(v0.w)+n1*us2f(v1.w)+n2*us2f(v2.w)+n3*us2f(v3.w);
            if(tail){
                ushort2 u0=((const ushort2*)p0)[128+lane], u1=((const ushort2*)p1)[128+lane];
                ushort2 u2=((const ushort2*)p2)[128+lane], u3=((const ushort2*)p3)[128+lane];
                t0 += n0*us2f(u0.x)+n1*us2f(u1.x)+n2*us2f(u2.x)+n3*us2f(u3.x);
                t1 += n0*us2f(u0.y)+n1*us2f(u1.y)+n2*us2f(u2.y)+n3*us2f(u3.y);
            }
        }
        for(; it < cnt; it++){
            int j0 = __shfl(jl, it);
            float n0 = di*__shfl(dl, it);
            const bf16* p0 = xs + (size_t)j0*EHD;
            ushort4 v0 = ((const ushort4*)p0)[lane];
            a0 += n0*us2f(v0.x); a1 += n0*us2f(v0.y); a2 += n0*us2f(v0.z); a3 += n0*us2f(v0.w);
            if(tail){
                ushort2 u0 = ((const ushort2*)p0)[128+lane];
                t0 += n0*us2f(u0.x); t1 += n0*us2f(u0.y);
            }
        }
    } else if(cnt > 64){
        for(int it=s0; it<s1; it++){
            int j = clampi(adjj[it], NN);
            float nr = di * dinv[j];
            const bf16* p0 = xs + (size_t)j*EHD;
            ushort4 v = ((const ushort4*)p0)[lane];
            a0 += nr*us2f(v.x); a1 += nr*us2f(v.y); a2 += nr*us2f(v.z); a3 += nr*us2f(v.w);
            if(tail){
                ushort2 u = ((const ushort2*)p0)[128+lane];
                t0 += nr*us2f(u.x); t1 += nr*us2f(u.y);
            }
        }
    }
    bf16* xo = xd + (size_t)n*EHD;
    ushort4 w0; w0.x=f2us(fmaxf(a0,0.f)); w0.y=f2us(fmaxf(a1,0.f)); w0.z=f2us(fmaxf(a2,0.f)); w0.w=f2us(fmaxf(a3,0.f));
    ((ushort4*)xo)[lane] = w0;
    if(tail){
        ushort2 w1; w1.x=f2us(fmaxf(t0,0.f)); w1.y=f2us(fmaxf(t1,0.f));
        ((ushort2*)xo)[128+lane] = w1;
    }
}

// ---------- MFMA GEMM ----------
template<int MODE>
__global__ __launch_bounds__(256) void k_gemm_mfma(const bf16* __restrict__ X,
                       const short* __restrict__ Wt, const float* __restrict__ bias,
                       bf16* __restrict__ out, const bf16* __restrict__ Xprev,
                       int M, int K, int Ncols){
    __shared__ short As[64][40];
    __shared__ short Bs[64][40];
    int tid = threadIdx.x;
    int bm = blockIdx.x*64, bn = blockIdx.y*64;
    int wid = tid>>6, lane = tid&63;
    int wm = (wid&1)*32, wn = (wid>>1)*32;
    int lm = lane&15, lq = lane>>4;
    f32x4_t acc00={0,0,0,0}, acc01={0,0,0,0}, acc10={0,0,0,0}, acc11={0,0,0,0};
    int mrow = tid>>2, kc = (tid&3)*8;
    union U8 { bf16x8_t v; uint2 u[2]; short s[8]; };
    for(int k0=0; k0<K; k0+=32){
        int gk0 = k0 + kc;
        {
            int gm = bm + mrow;
            U8 a;
            if(gm < M && gk0 + 8 <= K){
                const uint2* src = (const uint2*)(X + (size_t)gm*K + gk0);
                a.u[0] = src[0]; a.u[1] = src[1];
            } else {
                #pragma unroll
                for(int j=0;j<8;j++){
                    int gk = gk0 + j;
                    a.s[j] = (gm < M && gk < K) ? (short)*(const short*)(X + (size_t)gm*K + gk) : (short)0;
                }
                if(gm >= M){ a.u[0] = {0,0}; a.u[1] = {0,0}; }
            }
            *(bf16x8_t*)&As[mrow][kc] = a.v;
        }
        {
            int gn = bn + mrow;
            U8 b;
            if(gn < Ncols && gk0 + 8 <= K){
                const uint2* src = (const uint2*)(Wt + (size_t)gn*K + gk0);
                b.u[0] = src[0]; b.u[1] = src[1];
            } else {
                #pragma unroll
                for(int j=0;j<8;j++){
                    int gk = gk0 + j;
                    b.s[j] = (gn < Ncols && gk < K) ? Wt[(size_t)gn*K + gk] : (short)0;
                }
                if(gn >= Ncols){ b.u[0] = {0,0}; b.u[1] = {0,0}; }
            }
            *(bf16x8_t*)&Bs[mrow][kc] = b.v;
        }
        __syncthreads();
        bf16x8_t a0 = *(bf16x8_t*)&As[wm + lm][lq*8];
        bf16x8_t a1 = *(bf16x8_t*)&As[wm + 16 + lm][lq*8];
        bf16x8_t b0 = *(bf16x8_t*)&Bs[wn + lm][lq*8];
        bf16x8_t b1 = *(bf16x8_t*)&Bs[wn + 16 + lm][lq*8];
        acc00 = __builtin_amdgcn_mfma_f32_16x16x32_bf16(a0, b0, acc00, 0, 0, 0);
        acc01 = __builtin_amdgcn_mfma_f32_16x16x32_bf16(a0, b1, acc01, 0, 0, 0);
        acc10 = __builtin_amdgcn_mfma_f32_16x16x32_bf16(a1, b0, acc10, 0, 0, 0);
        acc11 = __builtin_amdgcn_mfma_f32_16x16x32_bf16(a1, b1, acc11, 0, 0, 0);
        __syncthreads();
    }
    #pragma unroll
    for(int tm=0;tm<2;tm++){
        #pragma unroll
        for(int tn=0;tn<2;tn++){
            f32x4_t a = tm==0 ? (tn==0 ? acc00 : acc01) : (tn==0 ? acc10 : acc11);
            int gn = bn + wn + tn*16 + lm;
            if(gn >= Ncols) continue;
            float bi = bias[gn];
            #pragma unroll
            for(int r=0;r<4;r++){
                int gm = bm + wm + tm*16 + lq*4 + r;
                if(gm >= M) continue;
                float t = a[r] + bi;
                size_t p = (size_t)gm*Ncols + gn;
                if(MODE == 0){
                    out[p] = f2b(t);
                } else {
                    float g = 1.f/(1.f + expf(-t));
                    out[p] = f2b(g*b2f(out[p]) + (1.f - g)*b2f(Xprev[p]));
                }
            }
        }
    }
}

// ---------- chunked per-relation partial sums (no atomics, no pre-zero) ----------
__global__ void k_relsum2(const bf16* __restrict__ s, const int* __restrict__ ht,
                          const int* __restrict__ off_r, const int* __restrict__ adj_r,
                          float* __restrict__ RFP){
    int r = blockIdx.x, c = blockIdx.y, d = threadIdx.x;   // 128 threads
    if(d >= THD) return;
    int s0 = off_r[r], s1 = off_r[r+1];
    int cnt = s1 - s0;
    float ah = 0.f, at2 = 0.f;
    if(cnt > 0){
        int per = (cnt + RCH - 1)/RCH;
        int lo = s0 + c*per, hi = lo + per; if(hi > s1) hi = s1;
        for(int it=lo; it<hi; it++){
            int e = clampi(adj_r[it], NE);
            int hh = clampi(ht[e], NN), tt = clampi(ht[NE + e], NN);
            ah  += b2f(s[(size_t)hh*THD + d]);
            at2 += b2f(s[(size_t)tt*THD + d]);
        }
    }
    float* dst = RFP + ((size_t)c*NR + r)*200;
    dst[d] = ah;
    dst[THD + d] = at2;
}

// ---------- fused: reduce partials + normalize + x_type + 3x ER GEMV + cvec ----------
__global__ __launch_bounds__(256) void k_relfin_er(const float* __restrict__ RFP,
                        const int* __restrict__ off_r,
                        const float* __restrict__ sr1w, const float* __restrict__ sr1b,
                        const float* w0, const float* b0, const float* w1, const float* b1,
                        const float* w2, const float* b2,
                        const float* ar1, const float* ar2, const float* ar3,
                        float* __restrict__ ER, float* __restrict__ cvec){
    int r = blockIdx.x, tid = threadIdx.x;
    __shared__ float rfs[304];
    __shared__ float red[4];
    int cnt = off_r[r+1] - off_r[r];
    if(tid < 200){
        float v = 0.f;
        #pragma unroll
        for(int c=0;c<RCH;c++) v += RFP[((size_t)c*NR + r)*200 + tid];
        v *= 1.f/(float)(cnt > 1 ? cnt : 1);
        rfs[100 + tid] = v;
    }
    __syncthreads();
    if(tid < 100){
        float v = 0.f;
        if(cnt > 0){
            v = sr1b[tid];
            for(int k=0;k<200;k++) v += rfs[100+k]*sr1w[k*RHD + tid];
        }
        rfs[tid] = v;
    }
    __syncthreads();
    for(int kk=0;kk<3;kk++){
        const float* w = kk==0 ? w0 : (kk==1 ? w1 : w2);
        const float* b = kk==0 ? b0 : (kk==1 ? b1 : b2);
        const float* a = kk==0 ? ar1 : (kk==1 ? ar2 : ar3);
        float pd = 0.f;
        for(int o = tid; o < EHD; o += 256){
            float v = b[o];
            for(int d=0; d<EHD; d++) v += rfs[d]*w[(size_t)d*EHD + o];
            ER[((size_t)kk*NR + r)*EHD + o] = v;
            pd += v*a[o];
        }
        pd = wred_sum(pd);
        if((tid & 63) == 0) red[tid>>6] = pd;
        __syncthreads();
        if(tid == 0) cvec[kk*NR + r] = red[0]+red[1]+red[2]+red[3];
        __syncthreads();
    }
}

// ---------- one r2e round on a register-resident x row ----------
__device__ __forceinline__ void r2e_round(float* xv, bool tail, int lane, int s0, int s1,
        const int* __restrict__ adjrel, const float* __restrict__ ERk,
        const float* __restrict__ ck, const float* __restrict__ anode){
    float4 am = ((const float4*)anode)[lane];
    float p = xv[0]*am.x + xv[1]*am.y + xv[2]*am.z + xv[3]*am.w;
    if(tail){
        float2 at = ((const float2*)anode)[128+lane];
        p += xv[4]*at.x + xv[5]*at.y;
    }
    p = wred_sum(p);
    int cnt = s1 - s0;
    if(cnt <= 0) return;
    float a0=0,a1=0,a2=0,a3=0, t0=0,t1=0;
    if(cnt <= 64){
        int rl = (lane < cnt) ? clampi(adjrel[s0+lane], NR) : 0;
        float lg = p + ck[rl];
        lg = lg > 0 ? lg : 0.01f*lg;
        float mx = wred_max((lane < cnt) ? lg : -1e30f);
        float ex = (lane < cnt) ? expf(lg - mx) : 0.f;
        float ss = wred_sum(ex);
        float al = ex/ss;
        int it = 0;
        for(; it+2 <= cnt; it += 2){
            int r0i = __shfl(rl, it), r1i = __shfl(rl, it+1);
            float q0 = __shfl(al, it), q1 = __shfl(al, it+1);
            const float* e0b = ERk + (size_t)r0i*EHD;
            const float* e1b = ERk + (size_t)r1i*EHD;
            float4 e0 = ((const float4*)e0b)[lane], e1 = ((const float4*)e1b)[lane];
            a0 += q0*e0.x + q1*e1.x; a1 += q0*e0.y + q1*e1.y;
            a2 += q0*e0.z + q1*e1.z; a3 += q0*e0.w + q1*e1.w;
            if(tail){
                float2 f0 = ((const float2*)e0b)[128+lane], f1 = ((const float2*)e1b)[128+lane];
                t0 += q0*f0.x + q1*f1.x; t1 += q0*f0.y + q1*f1.y;
            }
        }
        if(it < cnt){
            int r0i = __shfl(rl, it);
            float q0 = __shfl(al, it);
            const float* e0b = ERk + (size_t)r0i*EHD;
            float4 e0 = ((const float4*)e0b)[lane];
            a0 += q0*e0.x; a1 += q0*e0.y; a2 += q0*e0.z; a3 += q0*e0.w;
            if(tail){
                float2 f0 = ((const float2*)e0b)[128+lane];
                t0 += q0*f0.x; t1 += q0*f0.y;
            }
        }
    } else {
        float mx = -1e30f;
        for(int it=s0; it<s1; it++){
            float lg = p + ck[clampi(adjrel[it], NR)];
            lg = lg > 0 ? lg : 0.01f*lg;
            mx = fmaxf(mx, lg);
        }
        float ss = 0;
        for(int it=s0; it<s1; it++){
            float lg = p + ck[clampi(adjrel[it], NR)];
            lg = lg > 0 ? lg : 0.01f*lg;
            ss += expf(lg - mx);
        }
        for(int it=s0; it<s1; it++){
            int r = clampi(adjrel[it], NR);
            float lg = p + ck[r];
            lg = lg > 0 ? lg : 0.01f*lg;
            float a = expf(lg - mx)/ss;
            const float* e0b = ERk + (size_t)r*EHD;
            float4 e0 = ((const float4*)e0b)[lane];
            a0 += a*e0.x; a1 += a*e0.y; a2 += a*e0.z; a3 += a*e0.w;
            if(tail){
                float2 f0 = ((const float2*)e0b)[128+lane];
                t0 += a*f0.x; t1 += a*f0.y;
            }
        }
    }
    xv[0] += fmaxf(a0,0.f); xv[1] += fmaxf(a1,0.f); xv[2] += fmaxf(a2,0.f); xv[3] += fmaxf(a3,0.f);
    if(tail){
        xv[4] += fmaxf(t0,0.f); xv[5] += fmaxf(t1,0.f);
    }
}

// ---------- fused: three r2e rounds + ajv ----------
__global__ void k_r2e3(bf16* __restrict__ x,
                       const int* __restrict__ off_h, const int* __restrict__ adj_h,
                       const int* __restrict__ off_t, const int* __restrict__ adj_t,
                       const float* __restrict__ ER, const float* __restrict__ cvec,
                       const float* __restrict__ ahw, const float* __restrict__ atw,
                       const float* __restrict__ ah1w, const float* __restrict__ ajw,
                       float* __restrict__ ajv){
    int wid = threadIdx.x >> 6, lane = threadIdx.x & 63;
    int n = blockIdx.x*4 + wid;
    if(n >= NN) return;
    bool tail = lane < 22;
    bf16* xr = x + (size_t)n*EHD;
    float xv[6];
    {
        ushort4 v = ((const ushort4*)xr)[lane];
        xv[0]=us2f(v.x); xv[1]=us2f(v.y); xv[2]=us2f(v.z); xv[3]=us2f(v.w);
        if(tail){
            ushort2 u = ((const ushort2*)xr)[128+lane];
            xv[4]=us2f(u.x); xv[5]=us2f(u.y);
        } else { xv[4]=0; xv[5]=0; }
    }
    int h0 = off_h[n], h1 = off_h[n+1];
    int t0_ = off_t[n], t1_ = off_t[n+1];
    r2e_round(xv, tail, lane, h0, h1, adj_h, ER,                    cvec,      ahw);
    r2e_round(xv, tail, lane, t0_, t1_, adj_t, ER + (size_t)NR*EHD, cvec+NR,   atw);
    r2e_round(xv, tail, lane, h0, h1, adj_h, ER + (size_t)2*NR*EHD, cvec+2*NR, ah1w);
    {
        float4 am = ((const float4*)ajw)[lane];
        float p = xv[0]*am.x + xv[1]*am.y + xv[2]*am.z + xv[3]*am.w;
        if(tail){
            float2 at = ((const float2*)ajw)[128+lane];
            p += xv[4]*at.x + xv[5]*at.y;
        }
        p = wred_sum(p);
        if(lane == 0) ajv[n] = p;
    }
    ushort4 w0; w0.x=f2us(xv[0]); w0.y=f2us(xv[1]); w0.z=f2us(xv[2]); w0.w=f2us(xv[3]);
    ((ushort4*)xr)[lane] = w0;
    if(tail){
        ushort2 w1; w1.x=f2us(xv[4]); w1.y=f2us(xv[5]);
        ((ushort2*)xr)[128+lane] = w1;
    }
}

// ---------- final GAT + fc; lane-parallel softmax + unroll-4 gather ----------
__global__ void k_final(const bf16* __restrict__ x, const float* __restrict__ ajv,
                        const int* __restrict__ off, const int* __restrict__ adjj,
                        const float* __restrict__ aiw, const float* __restrict__ fcw,
                        const float* __restrict__ fcb, float* __restrict__ out){
    int wid = threadIdx.x >> 6, lane = threadIdx.x & 63;
    int n = blockIdx.x*4 + wid;
    if(n >= NN) return;
    bool tail = lane < 22;
    const bf16* xr = x + (size_t)n*EHD;
    ushort4 xv = ((const ushort4*)xr)[lane];
    ushort2 xt = tail ? ((const ushort2*)xr)[128+lane] : ushort2{0,0};
    float4 am = ((const float4*)aiw)[lane];
    float2 at = tail ? ((const float2*)aiw)[128+lane] : float2{0,0};
    float p = us2f(xv.x)*am.x + us2f(xv.y)*am.y + us2f(xv.z)*am.z + us2f(xv.w)*am.w;
    if(tail) p += us2f(xt.x)*at.x + us2f(xt.y)*at.y;
    p = wred_sum(p);
    int s0 = off[n], s1 = off[n+1], cnt = s1 - s0;
    float a0=0,a1=0,a2=0,a3=0, t0=0,t1=0;
    if(cnt > 0 && cnt <= 64){
        int jl = (lane < cnt) ? clampi(adjj[s0+lane], NN) : 0;
        float av = (lane < cnt) ? ajv[jl] : 0.f;
        float lg = p + av;
        lg = lg > 0 ? lg : 0.01f*lg;
        float mx = wred_max((lane < cnt) ? lg : -1e30f);
        float ex = (lane < cnt) ? expf(lg - mx) : 0.f;
        float ss = wred_sum(ex);
        float al = ex/ss;
        int it = 0;
        for(; it+4 <= cnt; it += 4){
            int j0=__shfl(jl,it), j1=__shfl(jl,it+1), j2=__shfl(jl,it+2), j3=__shfl(jl,it+3);
            float q0=__shfl(al,it), q1=__shfl(al,it+1), q2=__shfl(al,it+2), q3=__shfl(al,it+3);
            const bf16* p0 = x + (size_t)j0*EHD;
            const bf16* p1 = x + (size_t)j1*EHD;
            const bf16* p2 = x + (size_t)j2*EHD;
            const bf16* p3 = x + (size_t)j3*EHD;
            ushort4 v0=((const ushort4*)p0)[lane], v1=((const ushort4*)p1)[lane];
            ushort4 v2=((const ushort4*)p2)[lane], v3=((const ushort4*)p3)[lane];
            a0 += q0*us2f(v0.x)+q1*us2f(v1.x)+q2*us2f(v2.x)+q3*us2f(v3.x);
            a1 += q0*us2f(v0.y)+q1*us2f(v1.y)+q2*us2f(v2.y)+q3*us2f(v3.y);
            a2 += q0*us2f(v0.z)+q1*us2f(v1.z)+q2*us2f(v2.z)+q3*us2f(v3.z);
            a3 += q0*us2f(v0.w)+q1*us2f(v1.w)+q2*us2f(v2.w)+q3*us2f(v3.w);
            if(tail){
                ushort2 u0=((const ushort2*)p0)[128+lane], u1=((const ushort2*)p1)[128+lane];
                ushort2 u2=((const ushort2*)p2)[128+lane], u3=((const ushort2*)p3)[128+lane];
                t0 += q0*us2f(u0.x)+q1*us2f(u1.x)+q2*us2f(u2.x)+q3*us2f(u3.x);
                t1 += q0*us2f(u0.y)+q1*us2f(u1.y)+q2*us2f(u2.y)+q3*us2f(u3.y);
            }
        }
        for(; it < cnt; it++){
            int j0 = __shfl(jl, it);
            float q0 = __shfl(al, it);
            const bf16* p0 = x + (size_t)j0*EHD;
            ushort4 v0 = ((const ushort4*)p0)[lane];
            a0 += q0*us2f(v0.x); a1 += q0*us2f(v0.y); a2 += q0*us2f(v0.z); a3 += q0*us2f(v0.w);
            if(tail){
                ushort2 u0 = ((const ushort2*)p0)[128+lane];
                t0 += q0*us2f(u0.x); t1 += q0*us2f(u0.y);
            }
        }
    } else if(cnt > 64){
        float mx = -1e30f;
        for(int it=s0; it<s1; it++){
            float lg = p + ajv[clampi(adjj[it], NN)];
            lg = lg > 0 ? lg : 0.01f*lg;
            mx = fmaxf(mx, lg);
        }
        float ss = 0;
        for(int it=s0; it<s1; it++){
            float lg = p + ajv[clampi(adjj[it], NN)];
            lg = lg > 0 ? lg : 0.01f*lg;
            ss += expf(lg - mx);
        }
        for(int it=s0; it<s1; it++){
            int j = clampi(adjj[it], NN);
            float lg = p + ajv[j];
            lg = lg > 0 ? lg : 0.01f*lg;
            float a = expf(lg - mx)/ss;
            const bf16* p0 = x + (size_t)j*EHD;
            ushort4 v = ((const ushort4*)p0)[lane];
            a0 += a*us2f(v.x); a1 += a*us2f(v.y); a2 += a*us2f(v.z); a3 += a*us2f(v.w);
            if(tail){
                ushort2 u = ((const ushort2*)p0)[128+lane];
                t0 += a*us2f(u.x); t1 += a*us2f(u.y);
            }
        }
    }
    float4 f0 = ((const float4*)fcw)[lane];
    float4 g0 = ((const float4*)(fcw+EHD))[lane];
    float part = us2f(xv.x)*f0.x + us2f(xv.y)*f0.y + us2f(xv.z)*f0.z + us2f(xv.w)*f0.w
               + fmaxf(a0,0.f)*g0.x + fmaxf(a1,0.f)*g0.y + fmaxf(a2,0.f)*g0.z + fmaxf(a3,0.f)*g0.w;
    if(tail){
        float2 f1 = ((const float2*)fcw)[128+lane];
        float2 g1 = ((const float2*)(fcw+EHD))[128+lane];
        part += us2f(xt.x)*f1.x + us2f(xt.y)*f1.y
              + fmaxf(t0,0.f)*g1.x + fmaxf(t1,0.f)*g1.y;
    }
    part = wred_sum(part);
    if(lane == 0) out[n] = part + fcb[0];
}

extern "C" void kernel_launch(void* const* d_in, const int* in_sizes, int n_in,
                              void* d_out, int out_size, void* d_ws, size_t ws_size,
                              hipStream_t stream){
    const float* x_in = (const float*)d_in[0];
    const int*  ht   = (const int*)d_in[1];
    const int*  rel  = (const int*)d_in[2];
    const int*  ji   = (const int*)d_in[3];
    const float* hw1w=(const float*)d_in[5];  const float* hw1b=(const float*)d_in[6];
    const float* hw2w=(const float*)d_in[7];  const float* hw2b=(const float*)d_in[8];
    const float* tc1w=(const float*)d_in[9];  const float* tc1b=(const float*)d_in[10];
    const float* sr1w=(const float*)d_in[11]; const float* sr1b=(const float*)d_in[12];
    const float* wrw =(const float*)d_in[15]; const float* wrb =(const float*)d_in[16];
    const float* wr1w=(const float*)d_in[17]; const float* wr1b=(const float*)d_in[18];
    const float* wr2w=(const float*)d_in[19]; const float* wr2b=(const float*)d_in[20];
    const float* ahw =(const float*)d_in[21]; const float* ah1w=(const float*)d_in[22];
    const float* atw =(const float*)d_in[23];
    const float* ar1 =(const float*)d_in[24]; const float* ar2 =(const float*)d_in[25];
    const float* ar3 =(const float*)d_in[26];
    const float* aiw =(const float*)d_in[27]; const float* ajw =(const float*)d_in[28];
    const float* fcw =(const float*)d_in[29]; const float* fcb =(const float*)d_in[30];
    float* out = (float*)d_out;

    char* w = (char*)d_ws;
    auto alloc = [&](size_t bytes)->char*{ char* p = w; w += (bytes + 255)/256*256; return p; };
    bf16* xF = (bf16*)alloc((size_t)NN*EHD*2);   // 30 MB
    bf16* B  = (bf16*)alloc((size_t)NN*EHD*2);   // 30 MB; CSR tmp/bhist -> gcn agg/x1 -> rel tables
    char* Bc = (char*)B;
    // build-phase aliases (dead before k_gcn touches B)
    int2* tmp_all = (int2*)(Bc);                      // 4 MB
    int2* tmp_h   = (int2*)(Bc + 4u*1024*1024);       // 2 MB
    int2* tmp_t   = (int2*)(Bc + 8u*1024*1024);       // 2 MB
    int2* tmp_r   = (int2*)(Bc + 12u*1024*1024);      // 2 MB
    int*  bhist   = (int*)(Bc + 18u*1024*1024);       // 0.5 MB
    // rel-phase aliases (alive after highway2)
    bf16*  sbuf = (bf16*)(Bc);                        // 10 MB
    float* ER   = (float*)(Bc + 12u*1024*1024);       // 1.08 MB
    float* cvec = (float*)(Bc + 14u*1024*1024);       // 3.6 KB
    float* ajv  = (float*)(Bc + 15u*1024*1024);       // 200 KB
    float* RFP  = (float*)(Bc + 16u*1024*1024);       // 1.92 MB (partial rel sums)
    short* Wt1 = (short*)alloc((size_t)EHD*EHD*2);
    short* Wt2 = (short*)alloc((size_t)EHD*EHD*2);
    short* Wtc = (short*)alloc((size_t)EHD*THD*2);
    float* dinv = (float*)alloc((size_t)NN*4);
    int* off_all=(int*)alloc((NN+1)*4);
    int* adj_all=(int*)alloc((size_t)NEA*4);
    int* off_h  =(int*)alloc((NN+1)*4);
    int* adj_h  =(int*)alloc((size_t)NE*4);
    int* off_t  =(int*)alloc((NN+1)*4);
    int* adj_t  =(int*)alloc((size_t)NE*4);
    int* off_r  =(int*)alloc((NR+1)*4);
    int* adj_r  =(int*)alloc((size_t)NE*4);
    int* gbase  =(int*)alloc(4*129*4);
    int* gcur   =(int*)alloc(4*128*4);

    // prep: cast x + transpose weights + bucket histograms (one launch)
    const int NPREP = NN*EHD/4;
    k_prep<<<dim3((NPREP+255)/256), dim3(256), 0, stream>>>((const float4*)x_in, (ushort*)xF,
                                                            hw1w, hw2w, tc1w, Wt1, Wt2, Wtc,
                                                            ji, ht, rel, bhist);
    k_bscan<<<dim3(1), dim3(512), 0, stream>>>(bhist, gbase, gcur);
    k_bin<<<dim3(HB, 4), dim3(256), 0, stream>>>(ji, ht, rel, gcur,
                                                 tmp_all, tmp_h, tmp_t, tmp_r);
    k_place<<<dim3(NBN, 4), dim3(256), 0, stream>>>(gbase, tmp_all, tmp_h, tmp_t, tmp_r,
                                                    off_all, off_h, off_t, off_r,
                                                    adj_all, adj_h, adj_t, adj_r, dinv);

    const int nb4 = (NN+3)/4;
    const dim3 gg((NN+63)/64, (EHD+63)/64);
    // highway 1: B = gcn(xF); B = sig(xF@hw1+b)*B + (1-sig)*xF
    k_gcn<<<dim3(nb4), dim3(256), 0, stream>>>(xF, B, off_all, adj_all, dinv);
    k_gemm_mfma<1><<<gg, dim3(256), 0, stream>>>(xF, Wt1, hw1b, B, xF, NN, EHD, EHD);
    // highway 2
    k_gcn<<<dim3(nb4), dim3(256), 0, stream>>>(B, xF, off_all, adj_all, dinv);
    k_gemm_mfma<1><<<gg, dim3(256), 0, stream>>>(B, Wt2, hw2b, xF, B, NN, EHD, EHD);
    // rel tables
    k_gemm_mfma<0><<<dim3((NN+63)/64, (THD+63)/64), dim3(256), 0, stream>>>(xF, Wtc, tc1b, sbuf, xF, NN, EHD, THD);
    k_relsum2<<<dim3(NR, RCH), dim3(128), 0, stream>>>(sbuf, ht, off_r, adj_r, RFP);
    k_relfin_er<<<dim3(NR), dim3(256), 0, stream>>>(RFP, off_r, sr1w, sr1b,
                                                    wrw, wrb, wr1w, wr1b, wr2w, wr2b,
                                                    ar1, ar2, ar3, ER, cvec);
    // fused three r2e rounds + ajv
    k_r2e3<<<dim3(nb4), dim3(256), 0, stream>>>(xF, off_h, adj_h, off_t, adj_t, ER, cvec,
                                                ahw, atw, ah1w, ajw, ajv);
    // final GAT + fc
    k_final<<<dim3(nb4), dim3(256), 0, stream>>>(xF, ajv, off_all, adj_all, aiw, fcw, fcb, out);
}